// Round 1
// baseline (308.646 us; speedup 1.0000x reference)
//
#include <hip/hip_runtime.h>

#define EMB_N 50
#define EMBP 52          // padded row (16B aligned, pad zeros)
#define LQ 32
#define LD 256
#define KN 21
#define MMSTRIDE 264     // 256 + 8 pad -> phase-B reads are 2-way (free)

// ---------------- Kernel 0: normalize whole vocab into ws ----------------
__global__ __launch_bounds__(256) void vocab_norm_kernel(
    const float* __restrict__ emb, float* __restrict__ vn, int vocab)
{
  int r = blockIdx.x * 256 + threadIdx.x;
  if (r >= vocab) return;
  const float2* src = (const float2*)(emb + (size_t)r * EMB_N);  // 200B rows: 8B aligned
  float v[EMB_N];
  float ss = 0.f;
#pragma unroll
  for (int i = 0; i < EMB_N / 2; i++) {
    float2 t = src[i];
    v[2*i] = t.x; v[2*i+1] = t.y;
    ss = fmaf(t.x, t.x, ss);
    ss = fmaf(t.y, t.y, ss);
  }
  float inv = 1.0f / (sqrtf(ss) + 1e-13f);   // matches ref: x / (norm + 1e-13)
  float o[EMBP];
#pragma unroll
  for (int i = 0; i < EMB_N; i++) o[i] = v[i] * inv;
  o[50] = 0.f; o[51] = 0.f;                  // zero pad -> 52-wide dot == 50-wide dot
  float4* dst = (float4*)(vn + (size_t)r * EMBP);  // 208B rows: 16B aligned
#pragma unroll
  for (int i = 0; i < 13; i++)
    dst[i] = make_float4(o[4*i], o[4*i+1], o[4*i+2], o[4*i+3]);
}

// ---------------- Main kernel: one workgroup per batch item ----------------
__global__ __launch_bounds__(256) void knrm_main_kernel(
    const float* __restrict__ vn,
    const int* __restrict__ q1, const int* __restrict__ d1,
    const int* __restrict__ q2, const int* __restrict__ d2,
    const float* __restrict__ w0, const float* __restrict__ b0,
    const float* __restrict__ w1, const float* __restrict__ b1,
    const float* __restrict__ w2, const float* __restrict__ b2,
    float* __restrict__ out)
{
  __shared__ float mm[LQ * MMSTRIDE];
  __shared__ float ko[KN];
  __shared__ float h0s[10];
  __shared__ float h1s[5];
  __shared__ float lg[2];

  const int b = blockIdx.x;
  const int tid = threadIdx.x;

  for (int pair = 0; pair < 2; pair++) {
    const int* qp = pair ? q2 : q1;
    const int* dp = pair ? d2 : d1;

    if (tid < KN) ko[tid] = 0.f;  // visible to phase B via post-matmul barrier

    // ---- gather this thread's doc row into registers (fp32, normalized) ----
    int dtok = dp[b * LD + tid];
    float dv[EMBP];
    const float4* drow = (const float4*)(vn + (size_t)dtok * EMBP);
#pragma unroll
    for (int i = 0; i < 13; i++) {
      float4 t = drow[i];
      dv[4*i] = t.x; dv[4*i+1] = t.y; dv[4*i+2] = t.z; dv[4*i+3] = t.w;
    }

    // ---- phase A: mm column via SGPR-broadcast query rows ----
    const int* qrow = qp + b * LQ;
    for (int q = 0; q < LQ; q++) {
      int qtok = __builtin_amdgcn_readfirstlane(qrow[q]);  // force uniform -> s_load path
      const float* qv = vn + (size_t)qtok * EMBP;
      float acc = 0.f;
#pragma unroll
      for (int e = 0; e < EMBP; e++) acc = fmaf(qv[e], dv[e], acc);
      mm[q * MMSTRIDE + tid] = acc;   // consecutive tid -> conflict-free
    }
    __syncthreads();

    // ---- phase B: 21 RBF kernels, accumulate over this thread's 32 docs ----
    const int q  = tid >> 3;
    const int db = tid & 7;
    const float* mrow = &mm[q * MMSTRIDE + db];  // banks (8q+db)%32: 2-way = free
    float S[KN];
#pragma unroll
    for (int j = 0; j < KN; j++) S[j] = 0.f;

#pragma unroll 2
    for (int i = 0; i < LD / 8; i++) {
      float x = mrow[8 * i];
#pragma unroll
      for (int j = 0; j < 20; j++) {
        float mu = -0.95f + 0.1f * (float)j;   // MUS reversed order, sigma=0.1
        float t = x - mu;
        S[j] += __builtin_amdgcn_exp2f(-72.13475204f * t * t);  // 50*log2(e)
      }
      float te = x - 1.0f;                      // exact kernel, sigma=0.001
      S[20] += __builtin_amdgcn_exp2f(-721347.52f * te * te);   // 5e5*log2(e)
    }

    // ---- reduce: sum over 8 doc-slices (lanes), log1p, sum over q ----
#pragma unroll
    for (int j = 0; j < KN; j++) {
      float v = S[j];
      v += __shfl_xor(v, 1);
      v += __shfl_xor(v, 2);
      v += __shfl_xor(v, 4);        // all 8 lanes of a q-group now hold S_q[j]
      float l = (db == 0) ? log1pf(v) : 0.f;
      l += __shfl_xor(l, 8);
      l += __shfl_xor(l, 16);
      l += __shfl_xor(l, 32);       // lane0 of wave: sum over its 8 q's
      if ((tid & 63) == 0) atomicAdd(&ko[j], l);
    }
    __syncthreads();

    // ---- tiny MLP: 21 -> 10 -> 5 -> 1 ----
    if (tid < 10) {
      float h = b0[tid];
#pragma unroll
      for (int k = 0; k < KN; k++) h = fmaf(w0[tid * KN + k], ko[k], h);
      h0s[tid] = fmaxf(h, 0.f);
    }
    __syncthreads();
    if (tid < 5) {
      float h = b1[tid];
#pragma unroll
      for (int k = 0; k < 10; k++) h = fmaf(w1[tid * 10 + k], h0s[k], h);
      h1s[tid] = fmaxf(h, 0.f);
    }
    __syncthreads();
    if (tid == 0) {
      float h = b2[0];
#pragma unroll
      for (int k = 0; k < 5; k++) h = fmaf(w2[k], h1s[k], h);
      lg[pair] = h;
    }
    __syncthreads();
  }

  if (tid == 0) {
    float z = lg[0] - lg[1];
    out[b] = 1.0f / (1.0f + expf(-z));
  }
}

// ---------------- launch ----------------
extern "C" void kernel_launch(void* const* d_in, const int* in_sizes, int n_in,
                              void* d_out, int out_size, void* d_ws, size_t ws_size,
                              hipStream_t stream)
{
  const float* emb = (const float*)d_in[0];
  const float* w0  = (const float*)d_in[1];
  const float* b0  = (const float*)d_in[2];
  const float* w1  = (const float*)d_in[3];
  const float* b1  = (const float*)d_in[4];
  const float* w2  = (const float*)d_in[5];
  const float* b2  = (const float*)d_in[6];
  const int* q1 = (const int*)d_in[7];
  const int* dd1 = (const int*)d_in[8];
  const int* q2 = (const int*)d_in[9];
  const int* dd2 = (const int*)d_in[10];
  float* out = (float*)d_out;

  int vocab = in_sizes[0] / EMB_N;      // 100000
  int B = in_sizes[7] / LQ;             // 2048

  float* vn = (float*)d_ws;             // vocab * 52 * 4 = 20.8 MB

  vocab_norm_kernel<<<(vocab + 255) / 256, 256, 0, stream>>>(emb, vn, vocab);
  knrm_main_kernel<<<B, 256, 0, stream>>>(vn, q1, dd1, q2, dd2,
                                          w0, b0, w1, b1, w2, b2, out);
}

// Round 2
// 228.176 us; speedup vs baseline: 1.3527x; 1.3527x over previous
//
#include <hip/hip_runtime.h>

#define EMB_N 50
#define EMBP 52          // padded row (16B aligned, pad zeros)
#define LQ 32
#define LD 256
#define KN 21
#define MMSTRIDE 264     // 256 + 8 pad -> phase-B reads 2-way (free)

// ---------------- Kernel 0: normalize vocab, coalesced (8 lanes/row) ----------------
__global__ __launch_bounds__(256) void vocab_norm_kernel(
    const float* __restrict__ emb, float* __restrict__ vn, int vocab)
{
  int gid = blockIdx.x * 256 + threadIdx.x;
  int r = gid >> 3;          // row
  int c = gid & 7;           // 8-float chunk within row
  if (r >= vocab) return;
  const float* row = emb + (size_t)r * EMB_N;
  float v[8];
#pragma unroll
  for (int k = 0; k < 8; k++) v[k] = 0.f;
  float ss = 0.f;
  int e0 = c * 8;
  if (c < 6) {               // elems 8c..8c+7
    const float2* p = (const float2*)(row + e0);   // 8B aligned
#pragma unroll
    for (int k = 0; k < 4; k++) {
      float2 t = p[k];
      v[2*k] = t.x; v[2*k+1] = t.y;
      ss = fmaf(t.x, t.x, ss); ss = fmaf(t.y, t.y, ss);
    }
  } else if (c == 6) {       // elems 48,49
    float2 t = *(const float2*)(row + 48);
    v[0] = t.x; v[1] = t.y;
    ss = fmaf(t.x, t.x, t.y * t.y);
  }                          // c==7: nothing
  // row sum-of-squares across the 8-lane group (aligned within wave)
  ss += __shfl_xor(ss, 1);
  ss += __shfl_xor(ss, 2);
  ss += __shfl_xor(ss, 4);
  float inv = 1.0f / (sqrtf(ss) + 1e-13f);   // matches ref: x/(norm+1e-13)
  float4* dst = (float4*)(vn + (size_t)r * EMBP + e0);  // 16B aligned (208-B rows)
  if (c < 6) {
    dst[0] = make_float4(v[0]*inv, v[1]*inv, v[2]*inv, v[3]*inv);
    dst[1] = make_float4(v[4]*inv, v[5]*inv, v[6]*inv, v[7]*inv);
  } else if (c == 6) {
    dst[0] = make_float4(v[0]*inv, v[1]*inv, 0.f, 0.f);  // zero pad -> 52-dot exact
  }
}

// Cj = exp(-50*mu_j^2), mu_j = -0.95 + 0.1*j  (j=0..19); Cj[20]=1 (exact kernel)
__device__ __constant__ const float CJ[KN] = {
  2.5261639e-20f, 2.0469719e-16f, 6.1019363e-13f, 6.6915861e-10f, 2.6995785e-7f,
  4.0065297e-5f,  2.1874911e-3f,  4.3936937e-2f,  0.32465247f,    0.88249690f,
  0.88249690f,    0.32465247f,    4.3936937e-2f,  2.1874911e-3f,  4.0065297e-5f,
  2.6995785e-7f,  6.6915861e-10f, 6.1019363e-13f, 2.0469719e-16f, 2.5261639e-20f,
  1.0f
};

// ---------------- Main kernel: one workgroup per batch item ----------------
__global__ __launch_bounds__(256, 4) void knrm_main_kernel(
    const float* __restrict__ vn,
    const int* __restrict__ q1, const int* __restrict__ d1,
    const int* __restrict__ q2, const int* __restrict__ d2,
    const float* __restrict__ w0, const float* __restrict__ b0,
    const float* __restrict__ w1, const float* __restrict__ b1,
    const float* __restrict__ w2, const float* __restrict__ b2,
    float* __restrict__ out)
{
  __shared__ float mm[LQ * MMSTRIDE];
  __shared__ float ko[KN];
  __shared__ float h0s[10];
  __shared__ float h1s[5];
  __shared__ float lg[2];

  const int b = blockIdx.x;
  const int tid = threadIdx.x;

  for (int pair = 0; pair < 2; pair++) {
    const int* qp = pair ? q2 : q1;
    const int* dp = pair ? d2 : d1;

    if (tid < KN) ko[tid] = 0.f;  // visible to phase B via post-matmul barrier

    // ---- gather this thread's doc row into registers ----
    int dtok = dp[b * LD + tid];
    float dv[EMBP];
    const float4* drow = (const float4*)(vn + (size_t)dtok * EMBP);
#pragma unroll
    for (int i = 0; i < 13; i++) {
      float4 t = drow[i];
      dv[4*i] = t.x; dv[4*i+1] = t.y; dv[4*i+2] = t.z; dv[4*i+3] = t.w;
    }

    // ---- phase A: mm column via SGPR-broadcast query rows ----
    const int* qrow = qp + b * LQ;
#pragma unroll 2
    for (int q = 0; q < LQ; q++) {
      int qtok = __builtin_amdgcn_readfirstlane(qrow[q]);  // uniform -> s_load path
      const float* qv = vn + (size_t)qtok * EMBP;
      float acc = 0.f;
#pragma unroll
      for (int e = 0; e < EMBP; e++) acc = fmaf(qv[e], dv[e], acc);
      mm[q * MMSTRIDE + tid] = acc;
    }
    __syncthreads();

    // ---- phase B: geometric-recurrence RBF kernels ----
    // F_j(x) = G(x) * R(x)^(j-10) * Cj,  G = exp(-50x^2+5x), R = exp(10x)
    const int q  = tid >> 3;
    const int db = tid & 7;
    const float* mrow = &mm[q * MMSTRIDE + db];
    float U[20];
#pragma unroll
    for (int j = 0; j < 20; j++) U[j] = 0.f;
    float S20 = 0.f;

#pragma unroll 2
    for (int i = 0; i < LD / 8; i++) {
      float x = mrow[8 * i];
      // a = -50*log2e, b = 5*log2e, c = 10*log2e
      float gc = __builtin_amdgcn_exp2f(x * fmaf(-72.1347520f, x, 7.2134752f));
      float r  = __builtin_amdgcn_exp2f(14.4269504f * x);
      float ri = __builtin_amdgcn_rcpf(r);
      float p = gc;
#pragma unroll
      for (int j = 10; j < 20; j++) { U[j] += p; p *= r; }   // up chain
      float p2 = gc;
#pragma unroll
      for (int j = 9; j >= 0; j--) { p2 *= ri; U[j] += p2; } // down chain
      float t = x - 1.0f;                                    // exact kernel sigma=1e-3
      S20 += __builtin_amdgcn_exp2f(-721347.52f * (t * t));
    }

    // ---- reduce: sum over 8 doc-slices, scale by Cj, log1p, sum over q ----
#pragma unroll
    for (int j = 0; j < KN; j++) {
      float v = (j < 20) ? U[j] : S20;
      v += __shfl_xor(v, 1);
      v += __shfl_xor(v, 2);
      v += __shfl_xor(v, 4);        // 8 lanes of a q-group hold S_q[j]
      float y = fmaf(CJ[j], v, 1.0f);                     // y >= 1
      float l = 0.69314718f * __builtin_amdgcn_logf(y);   // log1p via v_log_f32
      l = (db == 0) ? l : 0.f;
      l += __shfl_xor(l, 8);
      l += __shfl_xor(l, 16);
      l += __shfl_xor(l, 32);
      if ((tid & 63) == 0) atomicAdd(&ko[j], l);
    }
    __syncthreads();

    // ---- tiny MLP: 21 -> 10 -> 5 -> 1 ----
    if (tid < 10) {
      float h = b0[tid];
#pragma unroll
      for (int k = 0; k < KN; k++) h = fmaf(w0[tid * KN + k], ko[k], h);
      h0s[tid] = fmaxf(h, 0.f);
    }
    __syncthreads();
    if (tid < 5) {
      float h = b1[tid];
#pragma unroll
      for (int k = 0; k < 10; k++) h = fmaf(w1[tid * 10 + k], h0s[k], h);
      h1s[tid] = fmaxf(h, 0.f);
    }
    __syncthreads();
    if (tid == 0) {
      float h = b2[0];
#pragma unroll
      for (int k = 0; k < 5; k++) h = fmaf(w2[k], h1s[k], h);
      lg[pair] = h;
    }
    __syncthreads();
  }

  if (tid == 0) {
    float z = lg[0] - lg[1];
    out[b] = 1.0f / (1.0f + expf(-z));
  }
}

// ---------------- launch ----------------
extern "C" void kernel_launch(void* const* d_in, const int* in_sizes, int n_in,
                              void* d_out, int out_size, void* d_ws, size_t ws_size,
                              hipStream_t stream)
{
  const float* emb = (const float*)d_in[0];
  const float* w0  = (const float*)d_in[1];
  const float* b0  = (const float*)d_in[2];
  const float* w1  = (const float*)d_in[3];
  const float* b1  = (const float*)d_in[4];
  const float* w2  = (const float*)d_in[5];
  const float* b2  = (const float*)d_in[6];
  const int* q1 = (const int*)d_in[7];
  const int* dd1 = (const int*)d_in[8];
  const int* q2 = (const int*)d_in[9];
  const int* dd2 = (const int*)d_in[10];
  float* out = (float*)d_out;

  int vocab = in_sizes[0] / EMB_N;      // 100000
  int B = in_sizes[7] / LQ;             // 2048

  float* vn = (float*)d_ws;             // vocab * 52 * 4 = 20.8 MB

  vocab_norm_kernel<<<(vocab * 8 + 255) / 256, 256, 0, stream>>>(emb, vn, vocab);
  knrm_main_kernel<<<B, 256, 0, stream>>>(vn, q1, dd1, q2, dd2,
                                          w0, b0, w1, b1, w2, b2, out);
}

// Round 3
// 189.697 us; speedup vs baseline: 1.6270x; 1.2028x over previous
//
#include <hip/hip_runtime.h>

#define EMB_N 50
#define KP 64            // bf16 plane row width (k padded 50->64)
#define LQ 32
#define LD 256
#define KN 21
#define MMSTRIDE 264     // 256 + 8 pad -> phase-B reads 2-way (free)

typedef short v8s __attribute__((ext_vector_type(8)));   // 8 bf16 = one MFMA frag
typedef float v4f __attribute__((ext_vector_type(4)));
typedef float v2f __attribute__((ext_vector_type(2)));

// split f into bf16 hi (truncate) + bf16 lo; hi+lo = f within ~2^-16 rel
__device__ inline short bf16_hi(float f, float* back) {
  unsigned u = __float_as_uint(f);
  short h = (short)(u >> 16);
  *back = __uint_as_float(u & 0xffff0000u);
  return h;
}

// ---------- Kernel 0: normalize vocab -> bf16 hi/lo planes [vocab][64] ----------
__global__ __launch_bounds__(256) void vocab_norm_kernel(
    const float* __restrict__ emb, short* __restrict__ vhi,
    short* __restrict__ vlo, int vocab)
{
  int gid = blockIdx.x * 256 + threadIdx.x;
  int r = gid >> 3;          // row
  int c = gid & 7;           // 8-elem chunk within padded row
  if (r >= vocab) return;
  const float* row = emb + (size_t)r * EMB_N;
  float v[8];
#pragma unroll
  for (int k = 0; k < 8; k++) v[k] = 0.f;
  float ss = 0.f;
  int e0 = c * 8;
  if (c < 6) {
    const float2* p = (const float2*)(row + e0);
#pragma unroll
    for (int k = 0; k < 4; k++) {
      float2 t = p[k];
      v[2*k] = t.x; v[2*k+1] = t.y;
      ss = fmaf(t.x, t.x, ss); ss = fmaf(t.y, t.y, ss);
    }
  } else if (c == 6) {
    float2 t = *(const float2*)(row + 48);
    v[0] = t.x; v[1] = t.y;
    ss = fmaf(t.x, t.x, t.y * t.y);
  }                          // c==7: all pad zeros
  ss += __shfl_xor(ss, 1);
  ss += __shfl_xor(ss, 2);
  ss += __shfl_xor(ss, 4);
  float inv = 1.0f / (sqrtf(ss) + 1e-13f);   // matches ref x/(norm+1e-13)
  short hi[8], lo[8];
#pragma unroll
  for (int k = 0; k < 8; k++) {
    float f = v[k] * inv;
    float back;
    hi[k] = bf16_hi(f, &back);
    float dummy;
    lo[k] = bf16_hi(f - back, &dummy);       // exact residual, then truncate
  }
  size_t o = (size_t)r * KP + e0;            // byte offset 128r+16c: 16B aligned
  *(uint4*)(vhi + o) = *(const uint4*)hi;
  *(uint4*)(vlo + o) = *(const uint4*)lo;
}

// Cj = exp(-50*mu_j^2), mu_j = -0.95 + 0.1*j (j=0..19); Cj[20]=1 (exact kernel)
__device__ __constant__ const float CJ[KN] = {
  2.5261639e-20f, 2.0469719e-16f, 6.1019363e-13f, 6.6915861e-10f, 2.6995785e-7f,
  4.0065297e-5f,  2.1874911e-3f,  4.3936937e-2f,  0.32465247f,    0.88249690f,
  0.88249690f,    0.32465247f,    4.3936937e-2f,  2.1874911e-3f,  4.0065297e-5f,
  2.6995785e-7f,  6.6915861e-10f, 6.1019363e-13f, 2.0469719e-16f, 2.5261639e-20f,
  1.0f
};

// ---------- Main kernel: one workgroup per batch item ----------
__global__ __launch_bounds__(256, 4) void knrm_main_kernel(
    const short* __restrict__ vhi, const short* __restrict__ vlo,
    const int* __restrict__ q1, const int* __restrict__ d1,
    const int* __restrict__ q2, const int* __restrict__ d2,
    const float* __restrict__ w0, const float* __restrict__ b0,
    const float* __restrict__ w1, const float* __restrict__ b1,
    const float* __restrict__ w2, const float* __restrict__ b2,
    float* __restrict__ out)
{
  __shared__ float mm[LQ * MMSTRIDE];
  __shared__ float ko[KN];
  __shared__ float h0s[10];
  __shared__ float h1s[5];
  __shared__ float lg[2];

  const int b = blockIdx.x;
  const int tid = threadIdx.x;
  const int wave = tid >> 6;
  const int lane = tid & 63;
  const int l15 = lane & 15;
  const int quad = lane >> 4;

  for (int pair = 0; pair < 2; pair++) {
    const int* qp = pair ? q2 : q1;
    const int* dp = pair ? d2 : d1;

    if (tid < KN) ko[tid] = 0.f;

    // ---- phase A: mm = Qn . Dn^T via split-bf16 MFMA ----
    // wave w: M-tile = w&1, N-tiles (w>>1)*8 .. +7
    const int mtile = wave & 1;
    const int n0 = (wave >> 1) * 8;

    int qtok = qp[b * LQ + mtile * 16 + l15];
    const short* qh = vhi + (size_t)qtok * KP + quad * 8;
    const short* ql = vlo + (size_t)qtok * KP + quad * 8;
    v8s Ah0 = *(const v8s*)(qh);        // k-step 0: k = quad*8 + j
    v8s Ah1 = *(const v8s*)(qh + 32);   // k-step 1: k = 32 + quad*8 + j
    v8s Al0 = *(const v8s*)(ql);
    v8s Al1 = *(const v8s*)(ql + 32);

#pragma unroll 2
    for (int n = n0; n < n0 + 8; n++) {
      int dtok = dp[b * LD + n * 16 + l15];
      const short* dh = vhi + (size_t)dtok * KP + quad * 8;
      const short* dl = vlo + (size_t)dtok * KP + quad * 8;
      v8s Bh0 = *(const v8s*)(dh);
      v8s Bh1 = *(const v8s*)(dh + 32);
      v8s Bl0 = *(const v8s*)(dl);
      v8s Bl1 = *(const v8s*)(dl + 32);
      v4f C = {0.f, 0.f, 0.f, 0.f};
      C = __builtin_amdgcn_mfma_f32_16x16x32_bf16(Ah0, Bh0, C, 0, 0, 0);
      C = __builtin_amdgcn_mfma_f32_16x16x32_bf16(Ah1, Bh1, C, 0, 0, 0);
      C = __builtin_amdgcn_mfma_f32_16x16x32_bf16(Ah0, Bl0, C, 0, 0, 0);
      C = __builtin_amdgcn_mfma_f32_16x16x32_bf16(Ah1, Bl1, C, 0, 0, 0);
      C = __builtin_amdgcn_mfma_f32_16x16x32_bf16(Al0, Bh0, C, 0, 0, 0);
      C = __builtin_amdgcn_mfma_f32_16x16x32_bf16(Al1, Bh1, C, 0, 0, 0);
      // C/D layout: row = quad*4 + reg, col = l15 (within 16x16 tile)
      int mrow = mtile * 16 + quad * 4;
      int mcol = n * 16 + l15;
#pragma unroll
      for (int r = 0; r < 4; r++)
        mm[(mrow + r) * MMSTRIDE + mcol] = C[r];
    }
    __syncthreads();

    // ---- phase B: packed geometric-recurrence RBF kernels ----
    // F_j(x) = gc * r^(j-10) * Cj,  gc = exp(-50x^2+5x), r = exp(10x)
    const int q  = tid >> 3;
    const int db = tid & 7;
    const float* mrow_p = &mm[q * MMSTRIDE + db];
    v2f U2[10];                       // .x: j=10+i (up), .y: j=9-i (down)
#pragma unroll
    for (int i = 0; i < 10; i++) U2[i] = (v2f){0.f, 0.f};
    float S20 = 0.f;

#pragma unroll 2
    for (int i = 0; i < LD / 8; i++) {
      float x = mrow_p[8 * i];
      float gc = __builtin_amdgcn_exp2f(x * fmaf(-72.1347520f, x, 7.2134752f));
      float ex = 14.4269504f * x;     // 10*log2(e)*x
      float r  = __builtin_amdgcn_exp2f(ex);
      float ri = __builtin_amdgcn_exp2f(-ex);
      v2f p  = {gc, gc * ri};
      v2f rr = {r, ri};
#pragma unroll
      for (int k2 = 0; k2 < 10; k2++) { U2[k2] += p; p *= rr; }  // v_pk_* pairs
      float t = x - 1.0f;             // exact kernel sigma=1e-3
      S20 += __builtin_amdgcn_exp2f(-721347.52f * (t * t));
    }

    // ---- reduce: 8 doc-slices -> Cj scale -> log1p -> sum over q ----
#pragma unroll
    for (int j = 0; j < KN; j++) {
      float v = (j < 10) ? U2[9 - j].y : (j < 20 ? U2[j - 10].x : S20);
      v += __shfl_xor(v, 1);
      v += __shfl_xor(v, 2);
      v += __shfl_xor(v, 4);
      float y = fmaf(CJ[j], v, 1.0f);                     // y >= 1
      float l = 0.69314718f * __builtin_amdgcn_logf(y);   // log1p
      l = (db == 0) ? l : 0.f;
      l += __shfl_xor(l, 8);
      l += __shfl_xor(l, 16);
      l += __shfl_xor(l, 32);
      if ((tid & 63) == 0) atomicAdd(&ko[j], l);
    }
    __syncthreads();

    // ---- tiny MLP: 21 -> 10 -> 5 -> 1 ----
    if (tid < 10) {
      float h = b0[tid];
#pragma unroll
      for (int k = 0; k < KN; k++) h = fmaf(w0[tid * KN + k], ko[k], h);
      h0s[tid] = fmaxf(h, 0.f);
    }
    __syncthreads();
    if (tid < 5) {
      float h = b1[tid];
#pragma unroll
      for (int k = 0; k < 10; k++) h = fmaf(w1[tid * 10 + k], h0s[k], h);
      h1s[tid] = fmaxf(h, 0.f);
    }
    __syncthreads();
    if (tid == 0) {
      float h = b2[0];
#pragma unroll
      for (int k = 0; k < 5; k++) h = fmaf(w2[k], h1s[k], h);
      lg[pair] = h;
    }
    __syncthreads();
  }

  if (tid == 0) {
    float z = lg[0] - lg[1];
    out[b] = 1.0f / (1.0f + expf(-z));
  }
}

// ---------------- launch ----------------
extern "C" void kernel_launch(void* const* d_in, const int* in_sizes, int n_in,
                              void* d_out, int out_size, void* d_ws, size_t ws_size,
                              hipStream_t stream)
{
  const float* emb = (const float*)d_in[0];
  const float* w0  = (const float*)d_in[1];
  const float* b0  = (const float*)d_in[2];
  const float* w1  = (const float*)d_in[3];
  const float* b1  = (const float*)d_in[4];
  const float* w2  = (const float*)d_in[5];
  const float* b2  = (const float*)d_in[6];
  const int* q1 = (const int*)d_in[7];
  const int* dd1 = (const int*)d_in[8];
  const int* q2 = (const int*)d_in[9];
  const int* dd2 = (const int*)d_in[10];
  float* out = (float*)d_out;

  int vocab = in_sizes[0] / EMB_N;      // 100000
  int B = in_sizes[7] / LQ;             // 2048

  short* vhi = (short*)d_ws;                           // 12.8 MB
  short* vlo = vhi + (size_t)vocab * KP;               // 12.8 MB

  vocab_norm_kernel<<<(vocab * 8 + 255) / 256, 256, 0, stream>>>(emb, vhi, vlo, vocab);
  knrm_main_kernel<<<B, 256, 0, stream>>>(vhi, vlo, q1, dd1, q2, dd2,
                                          w0, b0, w1, b1, w2, b2, out);
}